// Round 1
// baseline (307.273 us; speedup 1.0000x reference)
//
#include <hip/hip_runtime.h>
#include <math.h>

#define L 4096
#define B 8
#define D 1024
#define NH 16
#define COUT 128              // output chunk per block
#define WB 128                // windback length (q^128 <= 2.4e-6 worst-case here)
#define NCHUNK (L / COUT)     // 32
#define BD 8192               // B*D floats between consecutive l

#define REP16(F) F(0) F(1) F(2) F(3) F(4) F(5) F(6) F(7) F(8) F(9) F(10) F(11) F(12) F(13) F(14) F(15)
#define REP8(F)  F(0) F(1) F(2) F(3) F(4) F(5) F(6) F(7)

__device__ __forceinline__ float sigmoidf(float v) {
    return 1.0f / (1.0f + __expf(-v));
}

// Flat (non-nested) per-head update/accumulate macros — the preprocessor
// blue-paints a macro during its own expansion, so REP8/REP16 may not appear
// inside a macro that is itself expanded via them.
// Each thread now owns 8 heads (lane pairs split the 16 heads).
#define UPD(i) s##i = fmaf(q##i, s##i, xv);
#define UPDALL UPD(0) UPD(1) UPD(2) UPD(3) UPD(4) UPD(5) UPD(6) UPD(7)
#define ACC(i) s##i = fmaf(q##i, s##i, xv); y = fmaf(P##i, s##i, y);
#define ACCALL ACC(0) ACC(1) ACC(2) ACC(3) ACC(4) ACC(5) ACC(6) ACC(7)

// ---------------------------------------------------------------------------
// Head-split fused kernel: the 16 independent per-(b,d) head recurrences are
// split across adjacent lane pairs (even lane = heads 0-7, odd lane = heads
// 8-15 of the same d). This doubles the wave count (4096 -> 8192 = exact
// device fill at 32 waves/CU) at CONSTANT total FLOPs — the previous version
// was occupancy-starved (grid supplied only 4 of 8 possible waves/SIMD).
// Paired lanes load the same x address (coalescer merges; same line count),
// and per-step partial sums are combined with a cheap xor-1 shuffle
// (within-32-lane ds_swizzle). Even lane adds residual and stores.
// ---------------------------------------------------------------------------
__global__ void __launch_bounds__(256, 8)
ema_fused(const float* __restrict__ x,
          const float* __restrict__ damp,
          const float* __restrict__ decay,
          const float* __restrict__ ema,
          const float* __restrict__ proj,
          const float* __restrict__ rw,
          float* __restrict__ out) {
    const int tid  = threadIdx.x;
    const int lane = tid & 63;
    const int wv   = tid >> 6;            // wave in block: 0..3
    const int h    = lane & 1;            // head half: 0 -> heads 0-7, 1 -> heads 8-15
    const int dl   = lane >> 1;           // 0..31: d within wave
    const int d    = blockIdx.x * 128 + wv * 32 + dl;   // 0..1023
    const int c    = blockIdx.y;          // 0..NCHUNK-1
    const int b    = blockIdx.z;          // 0..7

    const float* dp = damp  + d * NH + h * 8;
    const float* dc = decay + d * NH + h * 8;
    const float* de = ema   + d * NH + h * 8;
    const float* pj = proj  + d * NH + h * 8;

    // ---- state: q (decay factor) and s (per-head EMA state), 8 heads ----
#define DECLQS(i) float q##i, s##i;
    REP8(DECLQS)
#define INITQS(i) { q##i = 1.0f - sigmoidf(dp[i]) * sigmoidf(dc[i]); s##i = 0.0f; }
    REP8(INITQS)

    const size_t base = (size_t)b * D + d;

    // ---- windback phase: advance state over [c*COUT - WB, c*COUT) ----
    if (c > 0) {
        const float* xp = x + (size_t)(c * COUT - WB) * BD + base;
#define LDA16(i) float a##i = xp[i * BD];
        REP16(LDA16)
        xp += 16 * BD;
        for (int r = 0; r < WB - 16; r += 16) {
#define LDB16(i) float t##i = xp[i * BD];
            REP16(LDB16)
            xp += 16 * BD;
#define CONS16(i) { float xv = a##i; UPDALL }
            REP16(CONS16)
#define MOV16(i) a##i = t##i;
            REP16(MOV16)
        }
        REP16(CONS16)   // consume final batch
    }

    // ---- projection weights + residual weight (kept dead during windback) ----
#define DECLP(i) float P##i;
    REP8(DECLP)
#define INITP(i) { float p_ = sigmoidf(dp[i]); P##i = p_ * de[i] * pj[i] * 0.25f; }
    REP8(INITP)
    // Only the even (h==0) lane of each pair adds the residual; odd lane
    // contributes 0 so the xor-1 combine yields exactly y_conv + x*w.
    const float weff = (h == 0) ? rw[d] : 0.0f;

    // ---- output phase: [c*COUT, (c+1)*COUT), 8-deep double-buffered ----
    const float* xp = x   + (size_t)(c * COUT) * BD + base;
    float*       op = out + (size_t)(c * COUT) * BD + base;

#define EMIT(v, k) { float xv = (v); float y = xv * weff; ACCALL \
                     y += __shfl_xor(y, 1); \
                     if (h == 0) __builtin_nontemporal_store(fmaxf(y, 0.0f), op + (k) * BD); }

#define LDA8(i) float a##i = xp[i * BD];
    REP8(LDA8)
    xp += 8 * BD;
    for (int r = 0; r < COUT - 8; r += 8) {
#define LDB8(i) float t##i = xp[i * BD];
        REP8(LDB8)
        xp += 8 * BD;
#define EM8(i) EMIT(a##i, i)
        REP8(EM8)
        op += 8 * BD;
#define MOV8(i) a##i = t##i;
        REP8(MOV8)
    }
    REP8(EM8)   // final batch
}

// ---------------------------------------------------------------------------
extern "C" void kernel_launch(void* const* d_in, const int* in_sizes, int n_in,
                              void* d_out, int out_size, void* d_ws, size_t ws_size,
                              hipStream_t stream) {
    const float* x     = (const float*)d_in[0];
    const float* damp  = (const float*)d_in[1];
    const float* decay = (const float*)d_in[2];
    const float* ema   = (const float*)d_in[3];
    const float* proj  = (const float*)d_in[4];
    const float* rw    = (const float*)d_in[5];
    float* out = (float*)d_out;

    // 2048 blocks x 4 waves = 8192 waves = exact device fill (256 CU x 32)
    dim3 grid(D / 128, NCHUNK, B);
    ema_fused<<<grid, 256, 0, stream>>>(x, damp, decay, ema, proj, rw, out);
}

// Round 2
// 283.173 us; speedup vs baseline: 1.0851x; 1.0851x over previous
//
#include <hip/hip_runtime.h>
#include <math.h>

#define L 4096
#define B 8
#define D 1024
#define NH 16
#define COUT 128              // output chunk per block
#define WB 128                // windback length (q^128 <= 2.4e-6 worst-case here)
#define NCHUNK (L / COUT)     // 32
#define BD 8192               // B*D floats between consecutive l
#define DBLK 128              // d-values per block
#define TL 16                 // l-rows per LDS tile

#define REP8(F)  F(0) F(1) F(2) F(3) F(4) F(5) F(6) F(7)

__device__ __forceinline__ float sigmoidf(float v) {
    return 1.0f / (1.0f + __expf(-v));
}

// Per-head update/accumulate (8 heads per thread; lane pairs split 16 heads).
#define UPD(i) s##i = fmaf(q##i, s##i, xv);
#define UPDALL UPD(0) UPD(1) UPD(2) UPD(3) UPD(4) UPD(5) UPD(6) UPD(7)
#define ACC(i) s##i = fmaf(q##i, s##i, xv); y = fmaf(P##i, s##i, y);
#define ACCALL ACC(0) ACC(1) ACC(2) ACC(3) ACC(4) ACC(5) ACC(6) ACC(7)

// async global->LDS, 16B per lane. LDS dest is WAVE-UNIFORM base + lane*16
// (m104); global src is per-lane. One instr = 64 lanes x 16B = 1KB = two
// contiguous l-rows of this block's 128-d slice.
#define GLD16(g, l) __builtin_amdgcn_global_load_lds( \
    (const __attribute__((address_space(1))) unsigned int*)(g), \
    (__attribute__((address_space(3))) unsigned int*)(l), 16, 0, 0)

// ---------------------------------------------------------------------------
// Round 2: LDS-staged x. Round 1 proved the kernel is NOT occupancy-starved
// (2x waves -> 0% speedup): the bottleneck is the request stream — scattered
// 128B wave-loads at 32KB stride, with per-wave batch drains exposing loaded
// HBM latency. This version stages x tiles (16 l x 128 d = 8KB) into LDS via
// global_load_lds width=16: 1KB contiguous per instruction, 8x fewer VMEM
// instructions, double-buffered with 8 blocks/CU for cross-block overlap.
// ---------------------------------------------------------------------------
__global__ void __launch_bounds__(256, 8)
ema_fused(const float* __restrict__ x,
          const float* __restrict__ damp,
          const float* __restrict__ decay,
          const float* __restrict__ ema,
          const float* __restrict__ proj,
          const float* __restrict__ rw,
          float* __restrict__ out) {
    const int tid  = threadIdx.x;
    const int lane = tid & 63;
    const int wv   = tid >> 6;            // wave in block: 0..3
    const int h    = lane & 1;            // head half: 0 -> heads 0-7, 1 -> 8-15
    const int dloc = (wv << 5) + (lane >> 1);   // 0..127: d within block
    const int d0   = blockIdx.x * DBLK;
    const int d    = d0 + dloc;
    const int c    = blockIdx.y;          // 0..NCHUNK-1
    const int b    = blockIdx.z;          // 0..7

    __shared__ float lds[2][TL * DBLK];   // 2 x 8KB

    const float* dp = damp  + d * NH + h * 8;
    const float* dc = decay + d * NH + h * 8;
    const float* de = ema   + d * NH + h * 8;
    const float* pj = proj  + d * NH + h * 8;

    // ---- per-head state: q (decay) and s (EMA state) ----
#define DECLQS(i) float q##i, s##i;
    REP8(DECLQS)
#define INITQS(i) { q##i = 1.0f - sigmoidf(dp[i]) * sigmoidf(dc[i]); s##i = 0.0f; }
    REP8(INITQS)
#define DECLP(i) float P##i;
    REP8(DECLP)
#define INITP(i) { float p_ = sigmoidf(dp[i]); P##i = p_ * de[i] * pj[i] * 0.25f; }
    REP8(INITP)
    // Only even lane of each pair adds residual; odd contributes 0 so the
    // xor-1 combine yields exactly y_conv + x*w.
    const float weff = (h == 0) ? rw[d] : 0.0f;

    const int nt = (c > 0) ? (WB + COUT) / TL : COUT / TL;   // 16 or 8 tiles
    const int wt = (c > 0) ? WB / TL : 0;                    // windback tiles

    // block's x base: start of windback (or chunk start for c==0)
    const float* xb = x + (size_t)(c * COUT - (c > 0 ? WB : 0)) * BD
                        + (size_t)b * D + d0;

    // staging geometry: wave wv covers rows 4wv..4wv+3 via 2 instrs
    const int scol = (lane & 31) << 2;          // float col within row (16B/lane)
    const int srow = (wv << 2) + (lane >> 5);   // per-lane row for instr 0

    // ---- prologue: stage tile 0 ----
    {
        const float* g0 = xb + (size_t)srow * BD + scol;
        float* l0 = &lds[0][(wv << 2) * DBLK];  // wave-uniform LDS base
        GLD16(g0, l0);
        GLD16(g0 + (size_t)2 * BD, l0 + 2 * DBLK);
    }
    __syncthreads();   // drains vmcnt(0): tile 0 resident

    float* opb = out + (size_t)(c * COUT) * BD + (size_t)b * D + d;

    for (int t = 0; t < nt; ++t) {
        // issue next tile's async loads (lands by next barrier)
        if (t + 1 < nt) {
            const float* g0 = xb + (size_t)((t + 1) * TL + srow) * BD + scol;
            float* l0 = &lds[(t + 1) & 1][(wv << 2) * DBLK];
            GLD16(g0, l0);
            GLD16(g0 + (size_t)2 * BD, l0 + 2 * DBLK);
        }
        const float* buf = lds[t & 1];
        if (t < wt) {
            // ---- windback tile: state update only ----
#pragma unroll
            for (int sl = 0; sl < TL; ++sl) {
                float xv = buf[sl * DBLK + dloc];
                UPDALL
            }
        } else {
            // ---- output tile: update + project + residual + relu ----
            float* op = opb + (size_t)(t - wt) * TL * BD;
#pragma unroll
            for (int sl = 0; sl < TL; ++sl) {
                float xv = buf[sl * DBLK + dloc];
                float y = xv * weff;
                ACCALL
                y += __shfl_xor(y, 1);
                if (h == 0)
                    __builtin_nontemporal_store(fmaxf(y, 0.0f), op + (size_t)sl * BD);
            }
        }
        __syncthreads();   // tile t+1 resident; all waves done with buf[t&1]
    }
}

// ---------------------------------------------------------------------------
extern "C" void kernel_launch(void* const* d_in, const int* in_sizes, int n_in,
                              void* d_out, int out_size, void* d_ws, size_t ws_size,
                              hipStream_t stream) {
    const float* x     = (const float*)d_in[0];
    const float* damp  = (const float*)d_in[1];
    const float* decay = (const float*)d_in[2];
    const float* ema   = (const float*)d_in[3];
    const float* proj  = (const float*)d_in[4];
    const float* rw    = (const float*)d_in[5];
    float* out = (float*)d_out;

    // 2048 blocks x 4 waves = 8192 waves; 8 blocks/CU (16KB LDS each)
    dim3 grid(D / DBLK, NCHUNK, B);
    ema_fused<<<grid, 256, 0, stream>>>(x, damp, decay, ema, proj, rw, out);
}